// Round 1
// baseline (517.052 us; speedup 1.0000x reference)
//
#include <hip/hip_runtime.h>
#include <hip/hip_bf16.h>
#include <stdint.h>

// Problem dims (fixed by reference): N=4, L=4096, E=1024, H=1024
#define NB 4
#define LS 4096
#define ED 1024
#define HD 1024
#define MR (NB * LS)            // 16384 flattened rows
#define SCALE_S (1.0f / 64.0f)  // 1/sqrt(L)

typedef __attribute__((ext_vector_type(8))) short bf16x8;  // 8 bf16 = 4 VGPRs (guide §3)
typedef __attribute__((ext_vector_type(4))) float f32x4;

__device__ __forceinline__ unsigned short f2bf(float f) {
    union { float f; uint32_t u; } x; x.f = f;
    uint32_t r = x.u + 0x7fffu + ((x.u >> 16) & 1u);  // RNE
    return (unsigned short)(r >> 16);
}
__device__ __forceinline__ float bf2f(unsigned int u) {
    union { uint32_t u; float f; } x; x.u = u << 16;
    return x.f;
}

// async global->LDS, 16B per lane; LDS dest is wave-uniform base + lane*16
__device__ __forceinline__ void load_lds16(const void* g, void* s) {
    __builtin_amdgcn_global_load_lds(
        (const __attribute__((address_space(1))) void*)g,
        (__attribute__((address_space(3))) void*)s, 16, 0, 0);
}

// fp32 -> bf16 cast, 4 elems/thread
__global__ void __launch_bounds__(256) cast_bf16_k(
    const float4* __restrict__ src, ushort4* __restrict__ dst, int n4)
{
    const int i = blockIdx.x * 256 + threadIdx.x;
    if (i < n4) {
        float4 v = src[i];
        ushort4 o;
        o.x = f2bf(v.x); o.y = f2bf(v.y); o.z = f2bf(v.z); o.w = f2bf(v.w);
        dst[i] = o;
    }
}

// C = A * B^T (+bias). A: M x K bf16 row-major. B: Ncols x K bf16 row-major.
// MODE 0: store C bf16 (+bias per col). MODE 1: denom[col] += sum_rows exp(scale*acc)
// m97 structure: 128x128 tile, BK=32, 4 waves each 64x64 (4x4 frags of 16x16x32).
template<int MODE>
__global__ void __launch_bounds__(256)
gemm_bt(const unsigned short* __restrict__ A,
        const unsigned short* __restrict__ B,
        const float* __restrict__ bias,
        unsigned short* __restrict__ C,
        float* __restrict__ denom,
        int M, int Ncols, int K, float scale)
{
    __shared__ unsigned short As[128 * 32];
    __shared__ unsigned short Bs[128 * 32];

    const int t = threadIdx.x;
    const int wid = t >> 6;
    const int lane = t & 63;
    const int quad = lane >> 4;
    const int l16 = lane & 15;
    const int m0 = (wid >> 1) * 64;  // wave's row offset in tile
    const int n0 = (wid & 1) * 64;   // wave's col offset in tile
    const long blockM = (long)blockIdx.y * 128;
    const long blockN = (long)blockIdx.x * 128;

    if (MODE == 1) {
        const size_t zoff = (size_t)blockIdx.z * (size_t)M * (size_t)K;
        A += zoff; B += zoff;
        denom += (size_t)blockIdx.z * (size_t)Ncols;
    }

    // Staging: chunk c = r*256 + t covers tile row c/4, k-elems (c%4)*8..+7 (16B).
    const char* a_g = (const char*)(A + (blockM + (t >> 2)) * (size_t)K + (size_t)((t & 3) * 8));
    const char* b_g = (const char*)(B + (blockN + (t >> 2)) * (size_t)K + (size_t)((t & 3) * 8));
    const size_t half = (size_t)64 * (size_t)K * 2;  // +64 rows, bytes

    char* a_s0 = (char*)As + wid * 1024;  // wave-uniform LDS bases
    char* b_s0 = (char*)Bs + wid * 1024;

    f32x4 acc[4][4] = {};

    for (int kt = 0; kt < K; kt += 32) {
        const int kb = kt * 2;
        load_lds16(a_g + kb,        a_s0);
        load_lds16(a_g + kb + half, a_s0 + 4096);
        load_lds16(b_g + kb,        b_s0);
        load_lds16(b_g + kb + half, b_s0 + 4096);
        __syncthreads();  // drains vmcnt before barrier (compiler-inserted)

        bf16x8 aF[4], bF[4];
        const char* AsB = (const char*)As;
        const char* BsB = (const char*)Bs;
#pragma unroll
        for (int mf = 0; mf < 4; mf++)
            aF[mf] = *(const bf16x8*)(AsB + ((m0 + mf * 16 + l16) * 32 + quad * 8) * 2);
#pragma unroll
        for (int nf = 0; nf < 4; nf++)
            bF[nf] = *(const bf16x8*)(BsB + ((n0 + nf * 16 + l16) * 32 + quad * 8) * 2);
#pragma unroll
        for (int mf = 0; mf < 4; mf++)
#pragma unroll
            for (int nf = 0; nf < 4; nf++)
                acc[mf][nf] = __builtin_amdgcn_mfma_f32_16x16x32_bf16(
                    aF[mf], bF[nf], acc[mf][nf], 0, 0, 0);
        __syncthreads();
    }

    if (MODE == 0) {
        // C/D layout: col = lane&15, row = quad*4 + reg (verified m89/m91)
#pragma unroll
        for (int nf = 0; nf < 4; nf++) {
            const int col = (int)blockN + n0 + nf * 16 + l16;
            const float bv = bias[col];
#pragma unroll
            for (int mf = 0; mf < 4; mf++) {
                const long rowb = blockM + m0 + mf * 16 + quad * 4;
#pragma unroll
                for (int r = 0; r < 4; r++)
                    C[(size_t)(rowb + r) * (size_t)Ncols + col] = f2bf(acc[mf][nf][r] + bv);
            }
        }
    } else {
#pragma unroll
        for (int nf = 0; nf < 4; nf++) {
            float s = 0.f;
#pragma unroll
            for (int mf = 0; mf < 4; mf++)
#pragma unroll
                for (int r = 0; r < 4; r++)
                    s += __expf(acc[mf][nf][r] * scale);
            // sum across quads (rows) -> full 64-row partial per column
            s += __shfl_xor(s, 16);
            s += __shfl_xor(s, 32);
            if (quad == 0)
                atomicAdd(&denom[(int)blockN + n0 + nf * 16 + l16], s);
        }
    }
}

// exp(S[l,l]/64): one wave per row, bf16 dot over H=1024
__global__ void __launch_bounds__(256) diag_exp_k(
    const unsigned short* __restrict__ Qb, const unsigned short* __restrict__ Kb,
    float* __restrict__ dexp)
{
    const int row = blockIdx.x * 4 + (threadIdx.x >> 6);
    const int lane = threadIdx.x & 63;
    const unsigned short* q = Qb + (size_t)row * HD + lane * 16;
    const unsigned short* k = Kb + (size_t)row * HD + lane * 16;
    float s = 0.f;
#pragma unroll
    for (int c = 0; c < 2; c++) {
        const uint4 qa = *(const uint4*)(q + c * 8);
        const uint4 ka = *(const uint4*)(k + c * 8);
        const unsigned int qs[4] = {qa.x, qa.y, qa.z, qa.w};
        const unsigned int ks[4] = {ka.x, ka.y, ka.z, ka.w};
#pragma unroll
        for (int j = 0; j < 4; j++) {
            s += bf2f(qs[j] & 0xffffu) * bf2f(ks[j] & 0xffffu);
            s += bf2f(qs[j] >> 16)     * bf2f(ks[j] >> 16);
        }
    }
#pragma unroll
    for (int off = 32; off >= 1; off >>= 1) s += __shfl_xor(s, off);
    if (lane == 0) dexp[row] = __expf(s * SCALE_S);
}

// out[row, :] = (dexp[row]/denom[row]) * V[row, :]
__global__ void __launch_bounds__(256) finalize_k(
    const unsigned short* __restrict__ Vb, const float* __restrict__ dexp,
    const float* __restrict__ denom, float* __restrict__ out)
{
    const int i = blockIdx.x * 256 + threadIdx.x;  // one 8-elem chunk
    const int row = i >> 7;                        // H/8 = 128 chunks per row
    const float sc = dexp[row] / denom[row];
    const uint4 v = *(const uint4*)(Vb + (size_t)i * 8);
    float4 o0, o1;
    o0.x = bf2f(v.x & 0xffffu) * sc; o0.y = bf2f(v.x >> 16) * sc;
    o0.z = bf2f(v.y & 0xffffu) * sc; o0.w = bf2f(v.y >> 16) * sc;
    o1.x = bf2f(v.z & 0xffffu) * sc; o1.y = bf2f(v.z >> 16) * sc;
    o1.z = bf2f(v.w & 0xffffu) * sc; o1.w = bf2f(v.w >> 16) * sc;
    float* op = out + (size_t)i * 8;
    *(float4*)op = o0;
    *(float4*)(op + 4) = o1;
}

extern "C" void kernel_launch(void* const* d_in, const int* in_sizes, int n_in,
                              void* d_out, int out_size, void* d_ws, size_t ws_size,
                              hipStream_t stream)
{
    (void)in_sizes; (void)n_in; (void)out_size; (void)ws_size;
    const float* X  = (const float*)d_in[0];
    const float* Wq = (const float*)d_in[1];
    const float* bq = (const float*)d_in[2];
    const float* Wk = (const float*)d_in[3];
    const float* bk = (const float*)d_in[4];
    const float* Wv = (const float*)d_in[5];
    const float* bv = (const float*)d_in[6];
    float* out = (float*)d_out;

    // workspace layout (~141 MB)
    char* p = (char*)d_ws;
    unsigned short* Xb  = (unsigned short*)p; p += (size_t)MR * ED * 2;
    unsigned short* Wqb = (unsigned short*)p; p += (size_t)HD * ED * 2;
    unsigned short* Wkb = (unsigned short*)p; p += (size_t)HD * ED * 2;
    unsigned short* Wvb = (unsigned short*)p; p += (size_t)HD * ED * 2;
    unsigned short* Qb  = (unsigned short*)p; p += (size_t)MR * HD * 2;
    unsigned short* Kb  = (unsigned short*)p; p += (size_t)MR * HD * 2;
    unsigned short* Vb  = (unsigned short*)p; p += (size_t)MR * HD * 2;
    float* dexp  = (float*)p; p += (size_t)MR * 4;
    float* denom = (float*)p; p += (size_t)MR * 4;

    // 1) casts to bf16
    cast_bf16_k<<<MR * ED / 4 / 256, 256, 0, stream>>>((const float4*)X,  (ushort4*)Xb,  MR * ED / 4);
    cast_bf16_k<<<HD * ED / 4 / 256, 256, 0, stream>>>((const float4*)Wq, (ushort4*)Wqb, HD * ED / 4);
    cast_bf16_k<<<HD * ED / 4 / 256, 256, 0, stream>>>((const float4*)Wk, (ushort4*)Wkb, HD * ED / 4);
    cast_bf16_k<<<HD * ED / 4 / 256, 256, 0, stream>>>((const float4*)Wv, (ushort4*)Wvb, HD * ED / 4);

    // 2) projections Q,K,V = X*W^T + b
    dim3 blk(256);
    dim3 gproj(HD / 128, MR / 128, 1);
    gemm_bt<0><<<gproj, blk, 0, stream>>>(Xb, Wqb, bq, Qb, nullptr, MR, HD, ED, 0.f);
    gemm_bt<0><<<gproj, blk, 0, stream>>>(Xb, Wkb, bk, Kb, nullptr, MR, HD, ED, 0.f);
    gemm_bt<0><<<gproj, blk, 0, stream>>>(Xb, Wvb, bv, Vb, nullptr, MR, HD, ED, 0.f);

    // 3) diagonal numerators exp(S[l,l]/64)
    diag_exp_k<<<MR / 4, 256, 0, stream>>>(Qb, Kb, dexp);

    // 4) column denominators: denom[n,b] = sum_a exp(S[n,a,b]/64)
    hipMemsetAsync(denom, 0, MR * sizeof(float), stream);
    dim3 gden(LS / 128, LS / 128, NB);
    gemm_bt<1><<<gden, blk, 0, stream>>>(Qb, Kb, nullptr, nullptr, denom, LS, LS, HD, SCALE_S);

    // 5) out = diag * V
    finalize_k<<<MR * HD / 8 / 256, 256, 0, stream>>>(Vb, dexp, denom, out);
}

// Round 2
// 395.834 us; speedup vs baseline: 1.3062x; 1.3062x over previous
//
#include <hip/hip_runtime.h>
#include <hip/hip_bf16.h>
#include <stdint.h>

// Problem dims (fixed): N=4, L=4096, E=1024, H=1024
#define NB 4
#define LS 4096
#define ED 1024
#define HD 1024
#define MR (NB * LS)            // 16384 flattened rows
#define SCALE_S (1.0f / 64.0f)  // 1/sqrt(L)

typedef __attribute__((ext_vector_type(8))) short bf16x8;  // 8 bf16 (4 VGPRs)
typedef __attribute__((ext_vector_type(8))) int   i32x8;   // 32 fp8 bytes (8 VGPRs)
typedef __attribute__((ext_vector_type(4))) float f32x4;

__device__ __forceinline__ unsigned short f2bf(float f) {
    union { float f; uint32_t u; } x; x.f = f;
    uint32_t r = x.u + 0x7fffu + ((x.u >> 16) & 1u);  // RNE
    return (unsigned short)(r >> 16);
}
__device__ __forceinline__ float bf2f(unsigned int u) {
    union { uint32_t u; float f; } x; x.u = u << 16;
    return x.f;
}
__device__ __forceinline__ unsigned char f2fp8(float v) {
    return (unsigned char)(__builtin_amdgcn_cvt_pk_fp8_f32(v, v, 0, false) & 0xff);
}

// async global->LDS, 16B/lane; LDS dest = wave-uniform base + lane*16
__device__ __forceinline__ void load_lds16(const void* g, void* s) {
    __builtin_amdgcn_global_load_lds(
        (const __attribute__((address_space(1))) void*)g,
        (__attribute__((address_space(3))) void*)s, 16, 0, 0);
}

// ---------------- casts ----------------
__global__ void __launch_bounds__(256) cast_x_k(
    const float4* __restrict__ src, ushort4* __restrict__ dst)
{
    const int i = blockIdx.x * 256 + threadIdx.x;
    const float4 v = src[i];
    ushort4 o; o.x = f2bf(v.x); o.y = f2bf(v.y); o.z = f2bf(v.z); o.w = f2bf(v.w);
    dst[i] = o;
}

// pack Wq,Wk,Wv -> contiguous bf16 [3072 x 1024]
__global__ void __launch_bounds__(256) cast_w_k(
    const float4* __restrict__ wq, const float4* __restrict__ wk,
    const float4* __restrict__ wv, ushort4* __restrict__ dst)
{
    const int i = blockIdx.x * 256 + threadIdx.x;  // 0 .. 3*2^18-1
    const int s = i >> 18, j = i & 0x3ffff;
    const float4 v = (s == 0 ? wq : s == 1 ? wk : wv)[j];
    ushort4 o; o.x = f2bf(v.x); o.y = f2bf(v.y); o.z = f2bf(v.z); o.w = f2bf(v.w);
    dst[i] = o;
}

// ---------------- fused QKV projection ----------------
// C[16384 x 3072] = Xb[16384 x 1024] * Wall[3072 x 1024]^T + bias
// cols 0-1023 -> Qb (bf16) + Qf8; 1024-2047 -> Kb (bf16) + Kf8; 2048-3071 -> V fp32 into d_out
__global__ void __launch_bounds__(256)
gemm_qkv(const unsigned short* __restrict__ A,
         const unsigned short* __restrict__ B,
         const float* __restrict__ bq, const float* __restrict__ bk,
         const float* __restrict__ bv,
         unsigned short* __restrict__ Qb, unsigned short* __restrict__ Kb,
         unsigned char* __restrict__ Qf8, unsigned char* __restrict__ Kf8,
         float* __restrict__ outV)
{
    __shared__ unsigned short As[128 * 32];
    __shared__ unsigned short Bs[128 * 32];

    const int t = threadIdx.x;
    const int wid = t >> 6, lane = t & 63, quad = lane >> 4, l16 = lane & 15;
    const int m0 = (wid >> 1) * 64, n0 = (wid & 1) * 64;
    const long blockM = (long)blockIdx.y * 128;
    const long blockN = (long)blockIdx.x * 128;

    const char* a_g = (const char*)(A + (blockM + (t >> 2)) * (size_t)ED + (size_t)((t & 3) * 8));
    const char* b_g = (const char*)(B + (blockN + (t >> 2)) * (size_t)ED + (size_t)((t & 3) * 8));
    const size_t half = (size_t)64 * ED * 2;

    char* a_s0 = (char*)As + wid * 1024;
    char* b_s0 = (char*)Bs + wid * 1024;

    f32x4 acc[4][4] = {};

    for (int kt = 0; kt < ED; kt += 32) {
        const int kb = kt * 2;
        load_lds16(a_g + kb,        a_s0);
        load_lds16(a_g + kb + half, a_s0 + 4096);
        load_lds16(b_g + kb,        b_s0);
        load_lds16(b_g + kb + half, b_s0 + 4096);
        __syncthreads();

        bf16x8 aF[4], bF[4];
        const char* AsB = (const char*)As;
        const char* BsB = (const char*)Bs;
#pragma unroll
        for (int mf = 0; mf < 4; mf++)
            aF[mf] = *(const bf16x8*)(AsB + ((m0 + mf * 16 + l16) * 32 + quad * 8) * 2);
#pragma unroll
        for (int nf = 0; nf < 4; nf++)
            bF[nf] = *(const bf16x8*)(BsB + ((n0 + nf * 16 + l16) * 32 + quad * 8) * 2);
#pragma unroll
        for (int mf = 0; mf < 4; mf++)
#pragma unroll
            for (int nf = 0; nf < 4; nf++)
                acc[mf][nf] = __builtin_amdgcn_mfma_f32_16x16x32_bf16(
                    aF[mf], bF[nf], acc[mf][nf], 0, 0, 0);
        __syncthreads();
    }

    // C/D layout: col = lane&15, row = quad*4 + reg (verified m89/m91)
#pragma unroll
    for (int nf = 0; nf < 4; nf++) {
        const int col = (int)blockN + n0 + nf * 16 + l16;  // 0..3071
        const int region = col >> 10;                      // wave-uniform per frag
        const int cc = col & 1023;
        const float bias = (region == 0 ? bq : region == 1 ? bk : bv)[cc];
#pragma unroll
        for (int mf = 0; mf < 4; mf++) {
            const long rowb = blockM + m0 + mf * 16 + quad * 4;
#pragma unroll
            for (int r = 0; r < 4; r++) {
                const float val = acc[mf][nf][r] + bias;
                const size_t idx = (size_t)(rowb + r) * 1024 + cc;
                if (region == 2) {
                    outV[idx] = val;
                } else if (region == 0) {
                    Qb[idx] = f2bf(val);
                    Qf8[idx] = f2fp8(val);
                } else {
                    Kb[idx] = f2bf(val);
                    Kf8[idx] = f2fp8(val);
                }
            }
        }
    }
}

// ---------------- fp8 MX denominator GEMM ----------------
// denom[n,b] += sum_a exp((Q[n,a]·K[n,b]) / 64), Q,K in fp8 e4m3, K-dim 1024.
// 128x128 tile, BK=128, mfma_scale_f32_16x16x128_f8f6f4 with unit scales.
// LDS 16B-chunk XOR swizzle by (row&7) to break the 128B-row bank collapse.
__global__ void __launch_bounds__(256)
gemm_f8_denom(const unsigned char* __restrict__ Qf8,
              const unsigned char* __restrict__ Kf8,
              float* __restrict__ denom)
{
    __shared__ __align__(16) unsigned char As[128 * 128];
    __shared__ __align__(16) unsigned char Bs[128 * 128];

    const int t = threadIdx.x;
    const int wid = t >> 6, lane = t & 63, quad = lane >> 4, l16 = lane & 15;
    const int m0 = (wid >> 1) * 64, n0 = (wid & 1) * 64;
    const size_t zoff = (size_t)blockIdx.z * LS * (size_t)HD;
    const unsigned char* A = Qf8 + zoff;
    const unsigned char* B = Kf8 + zoff;
    float* dn = denom + (size_t)blockIdx.z * LS;
    const long blockM = (long)blockIdx.y * 128;
    const long blockN = (long)blockIdx.x * 128;

    // staging: thread t -> row t>>3 (of each 32-row group), swizzled 16B chunk
    const int srow = t >> 3;
    const int schunk = (t & 7) ^ (srow & 7);
    const unsigned char* a_g = A + (blockM + srow) * (size_t)HD + schunk * 16;
    const unsigned char* b_g = B + (blockN + srow) * (size_t)HD + schunk * 16;

    f32x4 acc[4][4] = {};

    for (int kt = 0; kt < HD; kt += 128) {
#pragma unroll
        for (int c = 0; c < 4; c++) {
            load_lds16(a_g + (size_t)c * 32 * HD + kt, (char*)As + c * 4096 + wid * 1024);
            load_lds16(b_g + (size_t)c * 32 * HD + kt, (char*)Bs + c * 4096 + wid * 1024);
        }
        __syncthreads();

        i32x8 aF[4], bF[4];
#pragma unroll
        for (int mf = 0; mf < 4; mf++) {
            const int ra = m0 + mf * 16 + l16;
            const int key = ra & 7;
            const unsigned char* base = As + ra * 128;
            const int4 lo = *(const int4*)(base + (((2 * quad)     ^ key) * 16));
            const int4 hi = *(const int4*)(base + (((2 * quad + 1) ^ key) * 16));
            aF[mf][0] = lo.x; aF[mf][1] = lo.y; aF[mf][2] = lo.z; aF[mf][3] = lo.w;
            aF[mf][4] = hi.x; aF[mf][5] = hi.y; aF[mf][6] = hi.z; aF[mf][7] = hi.w;
        }
#pragma unroll
        for (int nf = 0; nf < 4; nf++) {
            const int rb = n0 + nf * 16 + l16;
            const int key = rb & 7;
            const unsigned char* base = Bs + rb * 128;
            const int4 lo = *(const int4*)(base + (((2 * quad)     ^ key) * 16));
            const int4 hi = *(const int4*)(base + (((2 * quad + 1) ^ key) * 16));
            bF[nf][0] = lo.x; bF[nf][1] = lo.y; bF[nf][2] = lo.z; bF[nf][3] = lo.w;
            bF[nf][4] = hi.x; bF[nf][5] = hi.y; bF[nf][6] = hi.z; bF[nf][7] = hi.w;
        }
#pragma unroll
        for (int mf = 0; mf < 4; mf++)
#pragma unroll
            for (int nf = 0; nf < 4; nf++)
                acc[mf][nf] = __builtin_amdgcn_mfma_scale_f32_16x16x128_f8f6f4(
                    aF[mf], bF[nf], acc[mf][nf],
                    0, 0,                    // cbsz=FP8, blgp=FP8
                    0, 0x7f7f7f7f,           // scale_a opsel, scale_a = 1.0 (E8M0 127)
                    0, 0x7f7f7f7f);          // scale_b opsel, scale_b = 1.0
        __syncthreads();
    }

#pragma unroll
    for (int nf = 0; nf < 4; nf++) {
        float s = 0.f;
#pragma unroll
        for (int mf = 0; mf < 4; mf++)
#pragma unroll
            for (int r = 0; r < 4; r++)
                s += __expf(acc[mf][nf][r] * SCALE_S);
        s += __shfl_xor(s, 16);
        s += __shfl_xor(s, 32);
        if (quad == 0)
            atomicAdd(&dn[(int)blockN + n0 + nf * 16 + l16], s);
    }
}

// ---------------- diagonal numerator: exp(S[l,l]/64), bf16 dot ----------------
__global__ void __launch_bounds__(256) diag_exp_k(
    const unsigned short* __restrict__ Qb, const unsigned short* __restrict__ Kb,
    float* __restrict__ dexp)
{
    const int row = blockIdx.x * 4 + (threadIdx.x >> 6);
    const int lane = threadIdx.x & 63;
    const unsigned short* q = Qb + (size_t)row * HD + lane * 16;
    const unsigned short* k = Kb + (size_t)row * HD + lane * 16;
    float s = 0.f;
#pragma unroll
    for (int c = 0; c < 2; c++) {
        const uint4 qa = *(const uint4*)(q + c * 8);
        const uint4 ka = *(const uint4*)(k + c * 8);
        const unsigned int qs[4] = {qa.x, qa.y, qa.z, qa.w};
        const unsigned int ks[4] = {ka.x, ka.y, ka.z, ka.w};
#pragma unroll
        for (int j = 0; j < 4; j++) {
            s += bf2f(qs[j] & 0xffffu) * bf2f(ks[j] & 0xffffu);
            s += bf2f(qs[j] >> 16)     * bf2f(ks[j] >> 16);
        }
    }
#pragma unroll
    for (int off = 32; off >= 1; off >>= 1) s += __shfl_xor(s, off);
    if (lane == 0) dexp[row] = __expf(s * SCALE_S);
}

// ---------------- finalize: out[row,:] *= dexp[row]/denom[row] (in place) ----------------
__global__ void __launch_bounds__(256) finalize_k(
    float* __restrict__ out, const float* __restrict__ dexp,
    const float* __restrict__ denom)
{
    const int row = blockIdx.x;
    const float sc = dexp[row] / denom[row];
    float4* p = (float4*)(out + (size_t)row * HD) + threadIdx.x;
    float4 v = *p;
    v.x *= sc; v.y *= sc; v.z *= sc; v.w *= sc;
    *p = v;
}

extern "C" void kernel_launch(void* const* d_in, const int* in_sizes, int n_in,
                              void* d_out, int out_size, void* d_ws, size_t ws_size,
                              hipStream_t stream)
{
    (void)in_sizes; (void)n_in; (void)out_size; (void)ws_size;
    const float* X  = (const float*)d_in[0];
    const float* Wq = (const float*)d_in[1];
    const float* bq = (const float*)d_in[2];
    const float* Wk = (const float*)d_in[3];
    const float* bk = (const float*)d_in[4];
    const float* Wv = (const float*)d_in[5];
    const float* bv = (const float*)d_in[6];
    float* out = (float*)d_out;

    // workspace layout (140.6 MB — same footprint as R1)
    char* p = (char*)d_ws;
    unsigned short* Xb   = (unsigned short*)p; p += (size_t)MR * ED * 2;   // 33.55 MB
    unsigned short* Wall = (unsigned short*)p; p += (size_t)3072 * ED * 2; //  6.29 MB
    unsigned short* Qb   = (unsigned short*)p; p += (size_t)MR * HD * 2;   // 33.55 MB
    unsigned short* Kb   = (unsigned short*)p; p += (size_t)MR * HD * 2;   // 33.55 MB
    unsigned char*  Qf8  = (unsigned char*)p;  p += (size_t)MR * HD;       // 16.78 MB
    unsigned char*  Kf8  = (unsigned char*)p;  p += (size_t)MR * HD;       // 16.78 MB
    float* dexp  = (float*)p; p += (size_t)MR * 4;
    float* denom = (float*)p; p += (size_t)MR * 4;

    // 1) casts
    cast_x_k<<<MR * ED / 4 / 256, 256, 0, stream>>>((const float4*)X, (ushort4*)Xb);
    cast_w_k<<<3 * ED * ED / 4 / 256, 256, 0, stream>>>(
        (const float4*)Wq, (const float4*)Wk, (const float4*)Wv, (ushort4*)Wall);

    // 2) fused QKV projection (Q,K -> bf16+fp8; V -> fp32 in d_out)
    dim3 blk(256);
    dim3 gqkv(3072 / 128, MR / 128);
    gemm_qkv<<<gqkv, blk, 0, stream>>>(Xb, Wall, bq, bk, bv, Qb, Kb, Qf8, Kf8, out);

    // 3) diagonal numerators (bf16 precision)
    diag_exp_k<<<MR / 4, 256, 0, stream>>>(Qb, Kb, dexp);

    // 4) column denominators via MX-fp8 GEMM
    hipMemsetAsync(denom, 0, MR * sizeof(float), stream);
    dim3 gden(LS / 128, LS / 128, NB);
    gemm_f8_denom<<<gden, blk, 0, stream>>>(Qf8, Kf8, denom);

    // 5) out *= diag/denom (in place on V)
    finalize_k<<<MR, blk, 0, stream>>>(out, dexp, denom);
}

// Round 3
// 379.505 us; speedup vs baseline: 1.3624x; 1.0430x over previous
//
#include <hip/hip_runtime.h>
#include <hip/hip_bf16.h>
#include <stdint.h>

// Problem dims (fixed): N=4, L=4096, E=1024, H=1024
#define NB 4
#define LS 4096
#define ED 1024
#define HD 1024
#define MR (NB * LS)            // 16384 flattened rows
#define SCALE_S (1.0f / 64.0f)  // 1/sqrt(L)

typedef __attribute__((ext_vector_type(8))) short bf16x8;  // 8 bf16 (4 VGPRs)
typedef __attribute__((ext_vector_type(8))) int   i32x8;   // 32 fp8 bytes (8 VGPRs)
typedef __attribute__((ext_vector_type(4))) float f32x4;

__device__ __forceinline__ unsigned short f2bf(float f) {
    union { float f; uint32_t u; } x; x.f = f;
    uint32_t r = x.u + 0x7fffu + ((x.u >> 16) & 1u);  // RNE
    return (unsigned short)(r >> 16);
}
__device__ __forceinline__ float bf2f(unsigned int u) {
    union { uint32_t u; float f; } x; x.u = u << 16;
    return x.f;
}

// async global->LDS, 16B/lane; LDS dest = wave-uniform base + lane*16
__device__ __forceinline__ void load_lds16(const void* g, void* s) {
    __builtin_amdgcn_global_load_lds(
        (const __attribute__((address_space(1))) void*)g,
        (__attribute__((address_space(3))) void*)s, 16, 0, 0);
}

// ---------------- casts ----------------
__global__ void __launch_bounds__(256) cast_x_k(
    const float4* __restrict__ src, ushort4* __restrict__ dst)
{
    const int i = blockIdx.x * 256 + threadIdx.x;
    const float4 v = src[i];
    ushort4 o; o.x = f2bf(v.x); o.y = f2bf(v.y); o.z = f2bf(v.z); o.w = f2bf(v.w);
    dst[i] = o;
}

// pack Wq,Wk,Wv -> contiguous bf16 [3072 x 1024]
__global__ void __launch_bounds__(256) cast_w_k(
    const float4* __restrict__ wq, const float4* __restrict__ wk,
    const float4* __restrict__ wv, ushort4* __restrict__ dst)
{
    const int i = blockIdx.x * 256 + threadIdx.x;  // 0 .. 3*2^18-1
    const int s = i >> 18, j = i & 0x3ffff;
    const float4 v = (s == 0 ? wq : s == 1 ? wk : wv)[j];
    ushort4 o; o.x = f2bf(v.x); o.y = f2bf(v.y); o.z = f2bf(v.z); o.w = f2bf(v.w);
    dst[i] = o;
}

// ---------------- fused QKV projection ----------------
// C[16384 x 3072] = Xb * Wall^T + bias. Region per block (blockN>>10):
//   0: Q -> Qb bf16 row-major + Qf8t (tiled fp8)
//   1: K -> Kb bf16 row-major + Kf8t (tiled fp8)
//   2: V -> fp32 into d_out
// MFMA operands SWAPPED: mfma(bF, aF) => lane&15 = A-row (C row), regs = 4
// consecutive C cols -> every store is a per-lane contiguous 4-element chunk.
// fp8 tiled layout: addr = (row>>4)*16384 + (col>>4)*256 + (row&15)*16 + (col&15)
__global__ void __launch_bounds__(256)
gemm_qkv(const unsigned short* __restrict__ A,
         const unsigned short* __restrict__ B,
         const float* __restrict__ bq, const float* __restrict__ bk,
         const float* __restrict__ bv,
         unsigned short* __restrict__ Qb, unsigned short* __restrict__ Kb,
         unsigned char* __restrict__ Qf8t, unsigned char* __restrict__ Kf8t,
         float* __restrict__ outV)
{
    __shared__ unsigned short As[128 * 32];
    __shared__ unsigned short Bs[128 * 32];

    const int t = threadIdx.x;
    const int wid = t >> 6, lane = t & 63, quad = lane >> 4, l16 = lane & 15;
    const int m0 = (wid >> 1) * 64, n0 = (wid & 1) * 64;
    const long blockM = (long)blockIdx.y * 128;
    const long blockN = (long)blockIdx.x * 128;

    const char* a_g = (const char*)(A + (blockM + (t >> 2)) * (size_t)ED + (size_t)((t & 3) * 8));
    const char* b_g = (const char*)(B + (blockN + (t >> 2)) * (size_t)ED + (size_t)((t & 3) * 8));
    const size_t half = (size_t)64 * ED * 2;

    char* a_s0 = (char*)As + wid * 1024;
    char* b_s0 = (char*)Bs + wid * 1024;

    f32x4 acc[4][4] = {};

    for (int kt = 0; kt < ED; kt += 32) {
        const int kb = kt * 2;
        load_lds16(a_g + kb,        a_s0);
        load_lds16(a_g + kb + half, a_s0 + 4096);
        load_lds16(b_g + kb,        b_s0);
        load_lds16(b_g + kb + half, b_s0 + 4096);
        __syncthreads();

        bf16x8 aF[4], bF[4];
        const char* AsB = (const char*)As;
        const char* BsB = (const char*)Bs;
#pragma unroll
        for (int mf = 0; mf < 4; mf++)
            aF[mf] = *(const bf16x8*)(AsB + ((m0 + mf * 16 + l16) * 32 + quad * 8) * 2);
#pragma unroll
        for (int nf = 0; nf < 4; nf++)
            bF[nf] = *(const bf16x8*)(BsB + ((n0 + nf * 16 + l16) * 32 + quad * 8) * 2);
#pragma unroll
        for (int mf = 0; mf < 4; mf++)
#pragma unroll
            for (int nf = 0; nf < 4; nf++)
                acc[mf][nf] = __builtin_amdgcn_mfma_f32_16x16x32_bf16(
                    bF[nf], aF[mf], acc[mf][nf], 0, 0, 0);  // swapped: row<->col
        __syncthreads();
    }

    const int region = (int)(blockN >> 10);  // block-uniform (1024 % 128 == 0)
    const float* bias = region == 0 ? bq : region == 1 ? bk : bv;

#pragma unroll
    for (int mf = 0; mf < 4; mf++) {
        const size_t row = (size_t)(blockM + m0 + mf * 16 + l16);
#pragma unroll
        for (int nf = 0; nf < 4; nf++) {
            const int col = (int)blockN + n0 + nf * 16 + quad * 4;  // 4 consecutive
            const int cc = col & 1023;
            const float4 b4 = *(const float4*)(bias + cc);
            const float v0 = acc[mf][nf][0] + b4.x;
            const float v1 = acc[mf][nf][1] + b4.y;
            const float v2 = acc[mf][nf][2] + b4.z;
            const float v3 = acc[mf][nf][3] + b4.w;
            if (region == 2) {
                float4 o; o.x = v0; o.y = v1; o.z = v2; o.w = v3;
                *(float4*)(outV + row * 1024 + cc) = o;
            } else {
                ushort4 o;
                o.x = f2bf(v0); o.y = f2bf(v1); o.z = f2bf(v2); o.w = f2bf(v3);
                uint32_t u = 0;
                u = __builtin_amdgcn_cvt_pk_fp8_f32(v0, v1, u, false);
                u = __builtin_amdgcn_cvt_pk_fp8_f32(v2, v3, u, true);
                const size_t f8 = (row >> 4) * 16384 + (size_t)(cc >> 4) * 256
                                + (row & 15) * 16 + (cc & 15);
                if (region == 0) {
                    *(ushort4*)(Qb + row * 1024 + cc) = o;
                    *(uint32_t*)(Qf8t + f8) = u;
                } else {
                    *(ushort4*)(Kb + row * 1024 + cc) = o;
                    *(uint32_t*)(Kf8t + f8) = u;
                }
            }
        }
    }
}

// ---------------- fp8 MX denominator GEMM ----------------
// denom[n,b] += sum_a exp((Q[n,a]·K[n,b])/64). Inputs in fragment-major tiled
// fp8 layout -> staging windows are contiguous 1KB global reads and fragments
// are 2 clean ds_read_b128 each (16B/lane stride-1: 2-way aliasing = free).
__global__ void __launch_bounds__(256)
gemm_f8_denom(const unsigned char* __restrict__ Qt,
              const unsigned char* __restrict__ Kt,
              float* __restrict__ denom)
{
    __shared__ __align__(16) unsigned char As[16384];
    __shared__ __align__(16) unsigned char Bs[16384];

    const int t = threadIdx.x;
    const int wid = t >> 6, lane = t & 63, quad = lane >> 4, l16 = lane & 15;
    const int m0 = (wid >> 1) * 64, n0 = (wid & 1) * 64;
    const size_t zoff = (size_t)blockIdx.z * LS * (size_t)HD;
    const unsigned char* A = Qt + zoff;
    const unsigned char* B = Kt + zoff;
    float* dn = denom + (size_t)blockIdx.z * LS;
    const int blockM = blockIdx.y * 128;
    const int blockN = blockIdx.x * 128;

    // staging: wave wid owns windows iw = wid*4+j; window = (group iw>>1, chunk-quad iw&1)
    size_t aoff[4], boff[4];
#pragma unroll
    for (int j = 0; j < 4; j++) {
        const int iw = wid * 4 + j;
        const size_t lo = (size_t)((iw & 1) * 4 + (lane >> 4)) * 256 + (size_t)(lane & 15) * 16;
        aoff[j] = ((size_t)(blockM >> 4) + (iw >> 1)) * 16384 + lo;
        boff[j] = ((size_t)(blockN >> 4) + (iw >> 1)) * 16384 + lo;
    }

    f32x4 acc[4][4] = {};

    for (int kt = 0; kt < 8; kt++) {           // 8 k-tiles of 128 bytes
        const size_t ko = (size_t)kt * 2048;   // 8 chunks * 256B per group
#pragma unroll
        for (int j = 0; j < 4; j++) {
            load_lds16(A + aoff[j] + ko, (char*)As + (wid * 4 + j) * 1024);
            load_lds16(B + boff[j] + ko, (char*)Bs + (wid * 4 + j) * 1024);
        }
        __syncthreads();

        i32x8 aF[4], bF[4];
#pragma unroll
        for (int mf = 0; mf < 4; mf++) {
            const int base = (((m0 >> 4) + mf) * 2048) + quad * 512 + l16 * 16;
            const int4 lo = *(const int4*)(As + base);
            const int4 hi = *(const int4*)(As + base + 256);
            aF[mf][0] = lo.x; aF[mf][1] = lo.y; aF[mf][2] = lo.z; aF[mf][3] = lo.w;
            aF[mf][4] = hi.x; aF[mf][5] = hi.y; aF[mf][6] = hi.z; aF[mf][7] = hi.w;
        }
#pragma unroll
        for (int nf = 0; nf < 4; nf++) {
            const int base = (((n0 >> 4) + nf) * 2048) + quad * 512 + l16 * 16;
            const int4 lo = *(const int4*)(Bs + base);
            const int4 hi = *(const int4*)(Bs + base + 256);
            bF[nf][0] = lo.x; bF[nf][1] = lo.y; bF[nf][2] = lo.z; bF[nf][3] = lo.w;
            bF[nf][4] = hi.x; bF[nf][5] = hi.y; bF[nf][6] = hi.z; bF[nf][7] = hi.w;
        }
#pragma unroll
        for (int mf = 0; mf < 4; mf++)
#pragma unroll
            for (int nf = 0; nf < 4; nf++)
                acc[mf][nf] = __builtin_amdgcn_mfma_scale_f32_16x16x128_f8f6f4(
                    aF[mf], bF[nf], acc[mf][nf],
                    0, 0,              // cbsz=FP8, blgp=FP8
                    0, 0x7f7f7f7f,     // scale_a = 1.0 (E8M0 127)
                    0, 0x7f7f7f7f);    // scale_b = 1.0
        __syncthreads();
    }

    // C/D layout (unswapped): col = lane&15 = K-row (output col), rows = quad*4+reg
#pragma unroll
    for (int nf = 0; nf < 4; nf++) {
        float s = 0.f;
#pragma unroll
        for (int mf = 0; mf < 4; mf++)
#pragma unroll
            for (int r = 0; r < 4; r++)
                s += __expf(acc[mf][nf][r] * SCALE_S);
        s += __shfl_xor(s, 16);
        s += __shfl_xor(s, 32);
        if (quad == 0)
            atomicAdd(&dn[blockN + n0 + nf * 16 + l16], s);
    }
}

// ---------------- diagonal numerator: exp(S[l,l]/64), bf16 dot ----------------
__global__ void __launch_bounds__(256) diag_exp_k(
    const unsigned short* __restrict__ Qb, const unsigned short* __restrict__ Kb,
    float* __restrict__ dexp)
{
    const int row = blockIdx.x * 4 + (threadIdx.x >> 6);
    const int lane = threadIdx.x & 63;
    const unsigned short* q = Qb + (size_t)row * HD + lane * 16;
    const unsigned short* k = Kb + (size_t)row * HD + lane * 16;
    float s = 0.f;
#pragma unroll
    for (int c = 0; c < 2; c++) {
        const uint4 qa = *(const uint4*)(q + c * 8);
        const uint4 ka = *(const uint4*)(k + c * 8);
        const unsigned int qs[4] = {qa.x, qa.y, qa.z, qa.w};
        const unsigned int ks[4] = {ka.x, ka.y, ka.z, ka.w};
#pragma unroll
        for (int j = 0; j < 4; j++) {
            s += bf2f(qs[j] & 0xffffu) * bf2f(ks[j] & 0xffffu);
            s += bf2f(qs[j] >> 16)     * bf2f(ks[j] >> 16);
        }
    }
#pragma unroll
    for (int off = 32; off >= 1; off >>= 1) s += __shfl_xor(s, off);
    if (lane == 0) dexp[row] = __expf(s * SCALE_S);
}

// ---------------- finalize: out[row,:] *= dexp[row]/denom[row] (in place) ----------------
__global__ void __launch_bounds__(256) finalize_k(
    float* __restrict__ out, const float* __restrict__ dexp,
    const float* __restrict__ denom)
{
    const int row = blockIdx.x;
    const float sc = dexp[row] / denom[row];
    float4* p = (float4*)(out + (size_t)row * HD) + threadIdx.x;
    float4 v = *p;
    v.x *= sc; v.y *= sc; v.z *= sc; v.w *= sc;
    *p = v;
}

extern "C" void kernel_launch(void* const* d_in, const int* in_sizes, int n_in,
                              void* d_out, int out_size, void* d_ws, size_t ws_size,
                              hipStream_t stream)
{
    (void)in_sizes; (void)n_in; (void)out_size; (void)ws_size;
    const float* X  = (const float*)d_in[0];
    const float* Wq = (const float*)d_in[1];
    const float* bq = (const float*)d_in[2];
    const float* Wk = (const float*)d_in[3];
    const float* bk = (const float*)d_in[4];
    const float* Wv = (const float*)d_in[5];
    const float* bv = (const float*)d_in[6];
    float* out = (float*)d_out;

    // workspace layout (140.6 MB — same proven footprint as R2)
    char* p = (char*)d_ws;
    unsigned short* Xb   = (unsigned short*)p; p += (size_t)MR * ED * 2;   // 33.55 MB
    unsigned short* Wall = (unsigned short*)p; p += (size_t)3072 * ED * 2; //  6.29 MB
    unsigned short* Qb   = (unsigned short*)p; p += (size_t)MR * HD * 2;   // 33.55 MB
    unsigned short* Kb   = (unsigned short*)p; p += (size_t)MR * HD * 2;   // 33.55 MB
    unsigned char*  Qf8t = (unsigned char*)p;  p += (size_t)MR * HD;       // 16.78 MB (tiled)
    unsigned char*  Kf8t = (unsigned char*)p;  p += (size_t)MR * HD;       // 16.78 MB (tiled)
    float* dexp  = (float*)p; p += (size_t)MR * 4;
    float* denom = (float*)p; p += (size_t)MR * 4;

    // 1) casts
    cast_x_k<<<MR * ED / 4 / 256, 256, 0, stream>>>((const float4*)X, (ushort4*)Xb);
    cast_w_k<<<3 * ED * ED / 4 / 256, 256, 0, stream>>>(
        (const float4*)Wq, (const float4*)Wk, (const float4*)Wv, (ushort4*)Wall);

    // 2) fused QKV projection (Q,K -> bf16 + tiled fp8; V -> fp32 in d_out)
    dim3 blk(256);
    dim3 gqkv(3072 / 128, MR / 128);
    gemm_qkv<<<gqkv, blk, 0, stream>>>(Xb, Wall, bq, bk, bv, Qb, Kb, Qf8t, Kf8t, out);

    // 3) diagonal numerators (bf16 precision)
    diag_exp_k<<<MR / 4, 256, 0, stream>>>(Qb, Kb, dexp);

    // 4) column denominators via MX-fp8 GEMM on tiled layout
    hipMemsetAsync(denom, 0, MR * sizeof(float), stream);
    dim3 gden(LS / 128, LS / 128, NB);
    gemm_f8_denom<<<gden, blk, 0, stream>>>(Qf8t, Kf8t, denom);

    // 5) out *= diag/denom (in place on V)
    finalize_k<<<MR, blk, 0, stream>>>(out, dexp, denom);
}